// Round 3
// baseline (137.250 us; speedup 1.0000x reference)
//
#include <hip/hip_runtime.h>

#define NC 320   // coalition size
#define DIM 512

// ===========================================================================
// K1 "big1": verified body (R0/R2), plus out-zero (replaces memset).
// grid 656 x 256.
//   b < 640 : split-K partials for q=x@Wq^T, k=x@Wk^T. z=b/40 (mat=z>>3,
//             ksplit=z&7), rem=b%40: i0=(rem/8)*64, c0=(rem%8)*64.
//             64x64 tile, BK=32, 4x4 micro, float4 stores to private slice.
//   b >= 640: hpart[b-640][e] = sum over a 32-wide d-chunk of Wv[d,e]*wA[d].
// ===========================================================================
__global__ __launch_bounds__(256) void big1(
    const float* __restrict__ x,
    const float* __restrict__ Wq, const float* __restrict__ Wk,
    const float* __restrict__ Wv, const float* __restrict__ Wc,
    float* __restrict__ partQK,   // [16][NC][DIM]
    float* __restrict__ hpart,    // [16][DIM]
    float* __restrict__ out)
{
  const int b = blockIdx.x;
  const int t = threadIdx.x;

  if (b == 0 && t == 0) out[0] = 0.f;   // visible to K2/K3 atomics via
                                        // stream dispatch ordering.

  if (b >= 640) {   // ---- hpart ----
    const int d0 = (b - 640) * 32;
    for (int ei = t; ei < DIM; ei += 256) {
      float s = 0.f;
      #pragma unroll
      for (int d = 0; d < 32; ++d)
        s = fmaf(Wv[(d0 + d) * DIM + ei], Wc[d0 + d], s);
      hpart[(b - 640) * DIM + ei] = s;
    }
    return;
  }

  // ---- split-K gemm partials (verified) ----
  __shared__ __align__(16) float As[32][68];   // [kk][row]
  __shared__ __align__(16) float Bs[32][68];   // [kk][col]

  const int z   = b / 40;
  const int rem = b % 40;
  const int i0  = (rem / 8) * 64;
  const int c0  = (rem % 8) * 64;
  const float* __restrict__ W = (z & 8) ? Wk : Wq;
  const int kb = (z & 7) * 64;

  const int sr = t >> 2;            // staged row/col 0..63
  const int kc = (t & 3) << 3;      // staged k offset 0,8,16,24
  const int ty = t >> 4;            // 0..15 row quad
  const int tx = t & 15;            // 0..15 col quad

  float acc[4][4] = {};
  const float* xp = x + (i0 + sr) * DIM + kc;
  const float* wp = W + (c0 + sr) * DIM + kc;

  for (int k0 = kb; k0 < kb + 64; k0 += 32) {
    const float4 xa = *(const float4*)(xp + k0);
    const float4 xb = *(const float4*)(xp + k0 + 4);
    const float4 wa = *(const float4*)(wp + k0);
    const float4 wb = *(const float4*)(wp + k0 + 4);
    __syncthreads();
    As[kc+0][sr]=xa.x; As[kc+1][sr]=xa.y; As[kc+2][sr]=xa.z; As[kc+3][sr]=xa.w;
    As[kc+4][sr]=xb.x; As[kc+5][sr]=xb.y; As[kc+6][sr]=xb.z; As[kc+7][sr]=xb.w;
    Bs[kc+0][sr]=wa.x; Bs[kc+1][sr]=wa.y; Bs[kc+2][sr]=wa.z; Bs[kc+3][sr]=wa.w;
    Bs[kc+4][sr]=wb.x; Bs[kc+5][sr]=wb.y; Bs[kc+6][sr]=wb.z; Bs[kc+7][sr]=wb.w;
    __syncthreads();
    #pragma unroll
    for (int kk = 0; kk < 32; ++kk) {
      const float4 a4 = *(const float4*)&As[kk][ty * 4];
      const float4 b4 = *(const float4*)&Bs[kk][tx * 4];
      const float a[4] = {a4.x, a4.y, a4.z, a4.w};
      const float bb[4] = {b4.x, b4.y, b4.z, b4.w};
      #pragma unroll
      for (int i = 0; i < 4; ++i)
        #pragma unroll
        for (int j = 0; j < 4; ++j)
          acc[i][j] = fmaf(a[i], bb[j], acc[i][j]);
    }
  }
  float* outq = partQK + (size_t)z * NC * DIM;
  #pragma unroll
  for (int i = 0; i < 4; ++i) {
    float4 o = {acc[i][0], acc[i][1], acc[i][2], acc[i][3]};
    *(float4*)&outq[(i0 + ty*4 + i) * DIM + c0 + tx*4] = o;
  }
}

// ===========================================================================
// K2 "reduce_qk_u": verified (R2). grid 640 x 256.
//   b < 320 : q/k = sum of 8 partials + bias (bias first, sp ascending).
//   b >= 320: u/uw body, r=b-320. u[r] = x[r].h + c;
//             atomicAdd(out, x[r].wx) (+NC*bc at r==0).
// ===========================================================================
__global__ __launch_bounds__(256) void reduce_qk_u(
    const float* __restrict__ partQK,
    const float* __restrict__ bq, const float* __restrict__ bk,
    const float* __restrict__ x,  const float* __restrict__ hpart,
    const float* __restrict__ bv, const float* __restrict__ Wc,
    const float* __restrict__ bc,
    float* __restrict__ q, float* __restrict__ k,
    float* __restrict__ u, float* __restrict__ out)
{
  const int b = blockIdx.x;
  const int t = threadIdx.x;

  if (b < 320) {   // ---- q/k reduce (verified) ----
    const int mat = b / 160;
    const int f   = (b % 160) * 256 + t;   // float4 index
    const int row = f >> 7;                // 128 float4 per row
    const int col = (f & 127) * 4;
    const float* bias = mat ? bk : bq;
    float4 s = *(const float4*)&bias[col];
    const size_t off = (size_t)row * DIM + col;
    #pragma unroll
    for (int sp = 0; sp < 8; ++sp) {
      const float4 p = *(const float4*)&partQK[(size_t)(mat*8+sp) * NC * DIM + off];
      s.x += p.x; s.y += p.y; s.z += p.z; s.w += p.w;
    }
    float* o = mat ? k : q;
    *(float4*)&o[off] = s;
    return;
  }

  // ---- u / uw (verified body) ----
  __shared__ float red[12];
  const int lane = t & 63;
  const int wave = t >> 6;
  const int r = b - 320;

  float cp = bv[t] * Wc[t] + bv[t + 256] * Wc[t + 256];
  float su = 0.f, sw = 0.f;
  for (int ei = t; ei < DIM; ei += 256) {
    float hs = 0.f;
    #pragma unroll
    for (int sp = 0; sp < 16; ++sp) hs += hpart[sp * DIM + ei];
    const float xv = x[r * DIM + ei];
    su = fmaf(xv, hs, su);
    sw = fmaf(xv, Wc[DIM + ei], sw);
  }
  #pragma unroll
  for (int off = 32; off; off >>= 1) {
    cp += __shfl_down(cp, off);
    su += __shfl_down(su, off);
    sw += __shfl_down(sw, off);
  }
  if (lane == 0) { red[wave] = cp; red[4 + wave] = su; red[8 + wave] = sw; }
  __syncthreads();
  if (t == 0) {
    const float c  = red[0] + red[1] + red[2] + red[3];
    const float sU = red[4] + red[5] + red[6] + red[7];
    float sW = red[8] + red[9] + red[10] + red[11];
    u[r] = sU + c;
    if (r == 0) sW += (float)NC * bc[0];
    atomicAdd(out, sW);
  }
}

// ===========================================================================
// K3 "rows_fused2": grid 320 x 320 — ONE query row per block (fixes R2's
// 160x2-serial configuration). Replaces scores GEMM + row_ops3; no partS.
//
// Thread t computes S[i][t] directly (k row t streamed from L2). The fmaf
// chain (8 chunk accumulators, d ascending, chunks summed ascending, *scale)
// and the tail (verbatim row_ops3 restricted to t<256) are the exact code
// that passed absmax=0.0 in round 2 — only the row mapping changed.
// ===========================================================================
__global__ __launch_bounds__(320) void rows_fused2(
    const float* __restrict__ qbuf, const float* __restrict__ kbuf,
    const float* __restrict__ u, float* __restrict__ out)
{
  const int i    = blockIdx.x;     // query row 0..319
  const int t    = threadIdx.x;    // 0..319
  const int lane = t & 63;
  const int wave = t >> 6;

  __shared__ __align__(16) float qA[DIM];
  __shared__ float e[NC];
  __shared__ float Warr[NC];
  __shared__ float Csuf[NC + 1];
  __shared__ float wred[4];

  // ---- stage q row ----
  for (int ei = t; ei < DIM; ei += 320)
    qA[ei] = qbuf[i * DIM + ei];
  __syncthreads();

  // ---- score row entry: thread t owns column j = t ----
  {
    const float* kj = kbuf + (size_t)t * DIM;
    float sa[8];
    #pragma unroll
    for (int z = 0; z < 8; ++z) {
      float a = 0.f;
      #pragma unroll
      for (int dd = 0; dd < 64; dd += 4) {
        const int d = z * 64 + dd;
        const float4 kv  = *(const float4*)(kj + d);
        const float4 qa4 = *(const float4*)&qA[d];
        a = fmaf(qa4.x, kv.x, a);
        a = fmaf(qa4.y, kv.y, a);
        a = fmaf(qa4.z, kv.z, a);
        a = fmaf(qa4.w, kv.w, a);
      }
      sa[z] = a;
    }
    const float scale = 0.044194173824159216f;  // 1/sqrt(512)
    float sA = sa[0];
    #pragma unroll
    for (int z = 1; z < 8; ++z) sA += sa[z];
    e[t] = sA * scale;
  }
  __syncthreads();

  // ---- tail: verbatim row_ops3 (verified), restricted to t<256 ----
  float m = -1e30f;
  if (t < 256) {
    for (int kk = t; kk < NC; kk += 256) m = fmaxf(m, e[kk]);
    #pragma unroll
    for (int off = 32; off; off >>= 1) m = fmaxf(m, __shfl_down(m, off));
    if (lane == 0) wred[wave] = m;
  }
  __syncthreads();
  m = fmaxf(fmaxf(wred[0], wred[1]), fmaxf(wred[2], wred[3]));

  if (t < 256)
    for (int kk = t; kk < NC; kk += 256) e[kk] = __expf(e[kk] - m);
  __syncthreads();

  if (wave == 0) {
    float carry = 0.f;
    #pragma unroll
    for (int c = 0; c < 5; ++c) {
      const int idx = c * 64 + lane;
      float val = e[idx];
      #pragma unroll
      for (int off = 1; off < 64; off <<= 1) {
        const float nv = __shfl_up(val, off);
        if (lane >= off) val += nv;
      }
      const float incl = val + carry;       // prefix sum S[idx+1]
      const int j = idx + 1;
      if (j < NC) Warr[j] = (j > i) ? 1.f / ((float)j * incl) : 0.f;
      carry += __shfl(val, 63);
    }
    if (lane == 0) Warr[0] = 0.f;

    carry = 0.f;
    #pragma unroll
    for (int c = 4; c >= 0; --c) {
      const int idx = c * 64 + lane;
      float val = Warr[idx];
      #pragma unroll
      for (int off = 1; off < 64; off <<= 1) {
        const float nv = __shfl_down(val, off);
        if (lane + off < 64) val += nv;
      }
      Csuf[idx] = val + carry;              // sum_{j>=idx} W[j]
      carry += __shfl(val, 0);
    }
    if (lane == 0) Csuf[NC] = 0.f;
  }
  __syncthreads();

  float acc = 0.f;
  if (t < 256) {
    for (int kk = t; kk < NC; kk += 256) {
      const int mm = (i > kk) ? i : kk;
      acc += e[kk] * Csuf[mm + 1] * u[kk];
    }
    #pragma unroll
    for (int off = 32; off; off >>= 1) acc += __shfl_down(acc, off);
  }
  __syncthreads();
  if (t < 256 && lane == 0) wred[wave] = acc;
  __syncthreads();
  if (t == 0)
    atomicAdd(out, wred[0] + wred[1] + wred[2] + wred[3]);
}

// ---------------------------------------------------------------------------
extern "C" void kernel_launch(void* const* d_in, const int* in_sizes, int n_in,
                              void* d_out, int out_size, void* d_ws, size_t ws_size,
                              hipStream_t stream) {
  const float* x  = (const float*)d_in[0];
  // d_in[1] = goal (unused by the reference forward)
  const float* Wq = (const float*)d_in[2];
  const float* bq = (const float*)d_in[3];
  const float* Wk = (const float*)d_in[4];
  const float* bk = (const float*)d_in[5];
  const float* Wv = (const float*)d_in[6];
  const float* bv = (const float*)d_in[7];
  const float* Wc = (const float*)d_in[8];
  const float* bc = (const float*)d_in[9];

  float* ws     = (float*)d_ws;
  float* partQK = ws;                          // 16*163840 = 2,621,440 floats
  float* qbuf   = partQK + 16 * NC * DIM;      //   163,840
  float* kbuf   = qbuf + NC * DIM;             //   163,840
  float* hpart  = kbuf + NC * DIM;             //     8,192
  float* u      = hpart + 16 * DIM;            //       320
  float* out    = (float*)d_out;

  big1<<<656, 256, 0, stream>>>(x, Wq, Wk, Wv, Wc, partQK, hpart, out);
  reduce_qk_u<<<640, 256, 0, stream>>>(partQK, bq, bk, x, hpart, bv, Wc, bc,
                                       qbuf, kbuf, u, out);
  rows_fused2<<<320, 320, 0, stream>>>(qbuf, kbuf, u, out);
}

// Round 4
// 105.258 us; speedup vs baseline: 1.3039x; 1.3039x over previous
//
#include <hip/hip_runtime.h>

#define NC 320   // coalition size
#define DIM 512

// ===========================================================================
// K1 "big1": verified body, plus out-zero (replaces memset dispatch).
// grid 656 x 256.
//   b < 640 : split-K partials for q=x@Wq^T, k=x@Wk^T. z=b/40 (mat=z>>3,
//             ksplit=z&7), rem=b%40: i0=(rem/8)*64, c0=(rem%8)*64.
//             64x64 tile, BK=32, 4x4 micro, float4 stores to private slice.
//   b >= 640: hpart[b-640][e] = sum over a 32-wide d-chunk of Wv[d,e]*wA[d].
// ===========================================================================
__global__ __launch_bounds__(256) void big1(
    const float* __restrict__ x,
    const float* __restrict__ Wq, const float* __restrict__ Wk,
    const float* __restrict__ Wv, const float* __restrict__ Wc,
    float* __restrict__ partQK,   // [16][NC][DIM]
    float* __restrict__ hpart,    // [16][DIM]
    float* __restrict__ out)
{
  const int b = blockIdx.x;
  const int t = threadIdx.x;

  if (b == 0 && t == 0) out[0] = 0.f;   // visible to later dispatches' atomics
                                        // via stream ordering.

  if (b >= 640) {   // ---- hpart ----
    const int d0 = (b - 640) * 32;
    for (int ei = t; ei < DIM; ei += 256) {
      float s = 0.f;
      #pragma unroll
      for (int d = 0; d < 32; ++d)
        s = fmaf(Wv[(d0 + d) * DIM + ei], Wc[d0 + d], s);
      hpart[(b - 640) * DIM + ei] = s;
    }
    return;
  }

  // ---- split-K gemm partials (verified) ----
  __shared__ __align__(16) float As[32][68];   // [kk][row]
  __shared__ __align__(16) float Bs[32][68];   // [kk][col]

  const int z   = b / 40;
  const int rem = b % 40;
  const int i0  = (rem / 8) * 64;
  const int c0  = (rem % 8) * 64;
  const float* __restrict__ W = (z & 8) ? Wk : Wq;
  const int kb = (z & 7) * 64;

  const int sr = t >> 2;            // staged row/col 0..63
  const int kc = (t & 3) << 3;      // staged k offset 0,8,16,24
  const int ty = t >> 4;            // 0..15 row quad
  const int tx = t & 15;            // 0..15 col quad

  float acc[4][4] = {};
  const float* xp = x + (i0 + sr) * DIM + kc;
  const float* wp = W + (c0 + sr) * DIM + kc;

  for (int k0 = kb; k0 < kb + 64; k0 += 32) {
    const float4 xa = *(const float4*)(xp + k0);
    const float4 xb = *(const float4*)(xp + k0 + 4);
    const float4 wa = *(const float4*)(wp + k0);
    const float4 wb = *(const float4*)(wp + k0 + 4);
    __syncthreads();
    As[kc+0][sr]=xa.x; As[kc+1][sr]=xa.y; As[kc+2][sr]=xa.z; As[kc+3][sr]=xa.w;
    As[kc+4][sr]=xb.x; As[kc+5][sr]=xb.y; As[kc+6][sr]=xb.z; As[kc+7][sr]=xb.w;
    Bs[kc+0][sr]=wa.x; Bs[kc+1][sr]=wa.y; Bs[kc+2][sr]=wa.z; Bs[kc+3][sr]=wa.w;
    Bs[kc+4][sr]=wb.x; Bs[kc+5][sr]=wb.y; Bs[kc+6][sr]=wb.z; Bs[kc+7][sr]=wb.w;
    __syncthreads();
    #pragma unroll
    for (int kk = 0; kk < 32; ++kk) {
      const float4 a4 = *(const float4*)&As[kk][ty * 4];
      const float4 b4 = *(const float4*)&Bs[kk][tx * 4];
      const float a[4] = {a4.x, a4.y, a4.z, a4.w};
      const float bb[4] = {b4.x, b4.y, b4.z, b4.w};
      #pragma unroll
      for (int i = 0; i < 4; ++i)
        #pragma unroll
        for (int j = 0; j < 4; ++j)
          acc[i][j] = fmaf(a[i], bb[j], acc[i][j]);
    }
  }
  float* outq = partQK + (size_t)z * NC * DIM;
  #pragma unroll
  for (int i = 0; i < 4; ++i) {
    float4 o = {acc[i][0], acc[i][1], acc[i][2], acc[i][3]};
    *(float4*)&outq[(i0 + ty*4 + i) * DIM + c0 + tx*4] = o;
  }
}

// ===========================================================================
// K2 "reduce_qk_u": verified (R2/R3). grid 640 x 256.
//   b < 320 : q/k = sum of 8 partials + bias (bias first, sp ascending).
//   b >= 320: u/uw body, r=b-320. u[r] = x[r].h + c;
//             atomicAdd(out, x[r].wx) (+NC*bc at r==0).
// ===========================================================================
__global__ __launch_bounds__(256) void reduce_qk_u(
    const float* __restrict__ partQK,
    const float* __restrict__ bq, const float* __restrict__ bk,
    const float* __restrict__ x,  const float* __restrict__ hpart,
    const float* __restrict__ bv, const float* __restrict__ Wc,
    const float* __restrict__ bc,
    float* __restrict__ q, float* __restrict__ k,
    float* __restrict__ u, float* __restrict__ out)
{
  const int b = blockIdx.x;
  const int t = threadIdx.x;

  if (b < 320) {   // ---- q/k reduce (verified) ----
    const int mat = b / 160;
    const int f   = (b % 160) * 256 + t;   // float4 index
    const int row = f >> 7;                // 128 float4 per row
    const int col = (f & 127) * 4;
    const float* bias = mat ? bk : bq;
    float4 s = *(const float4*)&bias[col];
    const size_t off = (size_t)row * DIM + col;
    #pragma unroll
    for (int sp = 0; sp < 8; ++sp) {
      const float4 p = *(const float4*)&partQK[(size_t)(mat*8+sp) * NC * DIM + off];
      s.x += p.x; s.y += p.y; s.z += p.z; s.w += p.w;
    }
    float* o = mat ? k : q;
    *(float4*)&o[off] = s;
    return;
  }

  // ---- u / uw (verified body) ----
  __shared__ float red[12];
  const int lane = t & 63;
  const int wave = t >> 6;
  const int r = b - 320;

  float cp = bv[t] * Wc[t] + bv[t + 256] * Wc[t + 256];
  float su = 0.f, sw = 0.f;
  for (int ei = t; ei < DIM; ei += 256) {
    float hs = 0.f;
    #pragma unroll
    for (int sp = 0; sp < 16; ++sp) hs += hpart[sp * DIM + ei];
    const float xv = x[r * DIM + ei];
    su = fmaf(xv, hs, su);
    sw = fmaf(xv, Wc[DIM + ei], sw);
  }
  #pragma unroll
  for (int off = 32; off; off >>= 1) {
    cp += __shfl_down(cp, off);
    su += __shfl_down(su, off);
    sw += __shfl_down(sw, off);
  }
  if (lane == 0) { red[wave] = cp; red[4 + wave] = su; red[8 + wave] = sw; }
  __syncthreads();
  if (t == 0) {
    const float c  = red[0] + red[1] + red[2] + red[3];
    const float sU = red[4] + red[5] + red[6] + red[7];
    float sW = red[8] + red[9] + red[10] + red[11];
    u[r] = sU + c;
    if (r == 0) sW += (float)NC * bc[0];
    atomicAdd(out, sW);
  }
}

// ===========================================================================
// K3 "scores": verbatim R0 scores body (split-K partials for S = q.k^T),
// grid 200 x 256. z=b/25, rem=b%25: i0=(rem/5)*64, j0=(rem%5)*64, kb=z*64.
// Coalesced LDS-tiled — this is the fast path R3's direct-dot tried to
// replace and couldn't beat.
// ===========================================================================
__global__ __launch_bounds__(256) void scores(
    const float* __restrict__ qbuf, const float* __restrict__ kbuf,
    float* __restrict__ partS)      // [8][NC][NC]
{
  const int b = blockIdx.x;
  const int t = threadIdx.x;

  __shared__ __align__(16) float As[32][68];
  __shared__ __align__(16) float Bs[32][68];

  const int z   = b / 25;
  const int rem = b % 25;
  const int i0  = (rem / 5) * 64;
  const int j0  = (rem % 5) * 64;
  const int kb  = z * 64;

  const int sr = t >> 2;
  const int kc = (t & 3) << 3;
  const int ty = t >> 4;
  const int tx = t & 15;

  float acc[4][4] = {};
  const float* qp = qbuf + (i0 + sr) * DIM + kc;
  const float* kp = kbuf + (j0 + sr) * DIM + kc;

  for (int k0 = kb; k0 < kb + 64; k0 += 32) {
    const float4 qa  = *(const float4*)(qp + k0);
    const float4 qb2 = *(const float4*)(qp + k0 + 4);
    const float4 ka  = *(const float4*)(kp + k0);
    const float4 kb4 = *(const float4*)(kp + k0 + 4);
    __syncthreads();
    As[kc+0][sr]=qa.x;  As[kc+1][sr]=qa.y;  As[kc+2][sr]=qa.z;  As[kc+3][sr]=qa.w;
    As[kc+4][sr]=qb2.x; As[kc+5][sr]=qb2.y; As[kc+6][sr]=qb2.z; As[kc+7][sr]=qb2.w;
    Bs[kc+0][sr]=ka.x;  Bs[kc+1][sr]=ka.y;  Bs[kc+2][sr]=ka.z;  Bs[kc+3][sr]=ka.w;
    Bs[kc+4][sr]=kb4.x; Bs[kc+5][sr]=kb4.y; Bs[kc+6][sr]=kb4.z; Bs[kc+7][sr]=kb4.w;
    __syncthreads();
    #pragma unroll
    for (int kk = 0; kk < 32; ++kk) {
      const float4 a4 = *(const float4*)&As[kk][ty * 4];
      const float4 b4 = *(const float4*)&Bs[kk][tx * 4];
      const float a[4] = {a4.x, a4.y, a4.z, a4.w};
      const float bb[4] = {b4.x, b4.y, b4.z, b4.w};
      #pragma unroll
      for (int i = 0; i < 4; ++i)
        #pragma unroll
        for (int j = 0; j < 4; ++j)
          acc[i][j] = fmaf(a[i], bb[j], acc[i][j]);
    }
  }
  float* outs = partS + (size_t)z * NC * NC;
  #pragma unroll
  for (int i = 0; i < 4; ++i) {
    float4 o = {acc[i][0], acc[i][1], acc[i][2], acc[i][3]};
    *(float4*)&outs[(i0 + ty*4 + i) * NC + j0 + tx*4] = o;
  }
}

// ===========================================================================
// K4 "row_ops3": verbatim R0 body. One block per query row i. e = scale *
// sum of 8 S-partials; softmax shift + prefix/suffix scans; contraction with
// u -> one atomicAdd(out) per block. grid 320 x 256.
// ===========================================================================
__global__ __launch_bounds__(256) void row_ops3(
    const float* __restrict__ partS, const float* __restrict__ u,
    float* __restrict__ out)
{
  const int i    = blockIdx.x;
  const int t    = threadIdx.x;
  const int lane = t & 63;
  const int wave = t >> 6;

  __shared__ float e[NC];
  __shared__ float Warr[NC];
  __shared__ float Csuf[NC + 1];
  __shared__ float wred[4];

  const float scale = 0.044194173824159216f;  // 1/sqrt(512)
  for (int kk = t; kk < NC; kk += 256) {
    float s = 0.f;
    #pragma unroll
    for (int sp = 0; sp < 8; ++sp)
      s += partS[(size_t)sp * NC * NC + i * NC + kk];
    e[kk] = s * scale;
  }
  __syncthreads();

  float m = -1e30f;
  for (int kk = t; kk < NC; kk += 256) m = fmaxf(m, e[kk]);
  #pragma unroll
  for (int off = 32; off; off >>= 1) m = fmaxf(m, __shfl_down(m, off));
  if (lane == 0) wred[wave] = m;
  __syncthreads();
  m = fmaxf(fmaxf(wred[0], wred[1]), fmaxf(wred[2], wred[3]));

  for (int kk = t; kk < NC; kk += 256) e[kk] = __expf(e[kk] - m);
  __syncthreads();

  if (wave == 0) {
    float carry = 0.f;
    #pragma unroll
    for (int c = 0; c < 5; ++c) {
      const int idx = c * 64 + lane;
      float val = e[idx];
      #pragma unroll
      for (int off = 1; off < 64; off <<= 1) {
        const float nv = __shfl_up(val, off);
        if (lane >= off) val += nv;
      }
      const float incl = val + carry;       // prefix sum S[idx+1]
      const int j = idx + 1;
      if (j < NC) Warr[j] = (j > i) ? 1.f / ((float)j * incl) : 0.f;
      carry += __shfl(val, 63);
    }
    if (lane == 0) Warr[0] = 0.f;

    carry = 0.f;
    #pragma unroll
    for (int c = 4; c >= 0; --c) {
      const int idx = c * 64 + lane;
      float val = Warr[idx];
      #pragma unroll
      for (int off = 1; off < 64; off <<= 1) {
        const float nv = __shfl_down(val, off);
        if (lane + off < 64) val += nv;
      }
      Csuf[idx] = val + carry;              // sum_{j>=idx} W[j]
      carry += __shfl(val, 0);
    }
    if (lane == 0) Csuf[NC] = 0.f;
  }
  __syncthreads();

  float acc = 0.f;
  for (int kk = t; kk < NC; kk += 256) {
    const int mm = (i > kk) ? i : kk;
    acc += e[kk] * Csuf[mm + 1] * u[kk];
  }
  #pragma unroll
  for (int off = 32; off; off >>= 1) acc += __shfl_down(acc, off);
  __syncthreads();
  if (lane == 0) wred[wave] = acc;
  __syncthreads();
  if (t == 0)
    atomicAdd(out, wred[0] + wred[1] + wred[2] + wred[3]);
}

// ---------------------------------------------------------------------------
extern "C" void kernel_launch(void* const* d_in, const int* in_sizes, int n_in,
                              void* d_out, int out_size, void* d_ws, size_t ws_size,
                              hipStream_t stream) {
  const float* x  = (const float*)d_in[0];
  // d_in[1] = goal (unused by the reference forward)
  const float* Wq = (const float*)d_in[2];
  const float* bq = (const float*)d_in[3];
  const float* Wk = (const float*)d_in[4];
  const float* bk = (const float*)d_in[5];
  const float* Wv = (const float*)d_in[6];
  const float* bv = (const float*)d_in[7];
  const float* Wc = (const float*)d_in[8];
  const float* bc = (const float*)d_in[9];

  float* ws     = (float*)d_ws;
  float* partQK = ws;                          // 16*163840 = 2,621,440 floats
  float* partS  = partQK + 16 * NC * DIM;      // 8*102400  =   819,200
  float* qbuf   = partS + 8 * NC * NC;         //   163,840
  float* kbuf   = qbuf + NC * DIM;             //   163,840
  float* hpart  = kbuf + NC * DIM;             //     8,192
  float* u      = hpart + 16 * DIM;            //       320
  float* out    = (float*)d_out;

  big1<<<656, 256, 0, stream>>>(x, Wq, Wk, Wv, Wc, partQK, hpart, out);
  reduce_qk_u<<<640, 256, 0, stream>>>(partQK, bq, bk, x, hpart, bv, Wc, bc,
                                       qbuf, kbuf, u, out);
  scores<<<200, 256, 0, stream>>>(qbuf, kbuf, partS);
  row_ops3<<<NC, 256, 0, stream>>>(partS, u, out);
}